// Round 1
// baseline (135.147 us; speedup 1.0000x reference)
//
#include <hip/hip_runtime.h>

#define D 256
#define C2LOG2E 2.8853900817779268f   // 2 / ln(2): exp(2s) = exp2(s * C2LOG2E)
#define EPS 1e-8f
#define NSPLIT 16                      // column splits for denom partials

typedef __attribute__((ext_vector_type(8))) __bf16 bf16x8;
typedef __attribute__((ext_vector_type(4))) __bf16 bf16x4;
typedef __attribute__((ext_vector_type(4))) float  f32x4;

// ---------------- Kernel A: row-normalize [z1;z2] -> bf16 fn ----------------
// One wave per row (D=256 -> 4 floats/lane).
__global__ __launch_bounds__(256) void normalize_kernel(
    const float* __restrict__ z1, const float* __restrict__ z2,
    __bf16* __restrict__ fn, int N) {
  int wid  = threadIdx.x >> 6;
  int lane = threadIdx.x & 63;
  int row  = blockIdx.x * 4 + wid;
  const float* src = (row < N) ? (z1 + (size_t)row * D)
                               : (z2 + (size_t)(row - N) * D);
  f32x4 v = *(const f32x4*)(src + lane * 4);
  float ss = v.x * v.x + v.y * v.y + v.z * v.z + v.w * v.w;
  #pragma unroll
  for (int m = 1; m < 64; m <<= 1) ss += __shfl_xor(ss, m, 64);
  float inv = 1.0f / fmaxf(sqrtf(ss), EPS);
  bf16x4 o;
  o[0] = (__bf16)(v.x * inv);
  o[1] = (__bf16)(v.y * inv);
  o[2] = (__bf16)(v.z * inv);
  o[3] = (__bf16)(v.w * inv);
  *(bf16x4*)(fn + (size_t)row * D + lane * 4) = o;
}

// ---------------- Kernel P: pos_i = cos(z1_i, z2_i) in fp32 ----------------
__global__ __launch_bounds__(256) void pos_kernel(
    const float* __restrict__ z1, const float* __restrict__ z2,
    float* __restrict__ pos, int N) {
  int wid  = threadIdx.x >> 6;
  int lane = threadIdx.x & 63;
  int row  = blockIdx.x * 4 + wid;
  f32x4 a = *(const f32x4*)(z1 + (size_t)row * D + lane * 4);
  f32x4 b = *(const f32x4*)(z2 + (size_t)row * D + lane * 4);
  float dot = a.x * b.x + a.y * b.y + a.z * b.z + a.w * b.w;
  float n1  = a.x * a.x + a.y * a.y + a.z * a.z + a.w * a.w;
  float n2  = b.x * b.x + b.y * b.y + b.z * b.z + b.w * b.w;
  #pragma unroll
  for (int m = 1; m < 64; m <<= 1) {
    dot += __shfl_xor(dot, m, 64);
    n1  += __shfl_xor(n1, m, 64);
    n2  += __shfl_xor(n2, m, 64);
  }
  if (lane == 0)
    pos[row] = dot / (fmaxf(sqrtf(n1), EPS) * fmaxf(sqrtf(n2), EPS));
}

// -------- Kernel B: denom partials via MFMA: sum_j!=i exp(2*fn_i.fn_j) -----
// Grid: (twoN/256 row-blocks) x NSPLIT col-splits. Block = 4 waves, each wave
// owns 64 rows x 512 cols. No LDS, no barriers: A/B fragments straight from
// L2-resident fn. mfma_f32_16x16x32_bf16: A row=lane&15, k=(lane>>4)*8+j;
// C/D col=lane&15, row=(lane>>4)*4+reg  (m89/m91-verified layouts).
__global__ __launch_bounds__(256) void denom_kernel(
    const __bf16* __restrict__ fn, float* __restrict__ partial, int twoN) {
  int wid  = threadIdx.x >> 6;
  int lane = threadIdx.x & 63;
  int c = lane & 15;        // A-row / B-col / D-col within 16-tile
  int g = lane >> 4;        // k-group (input) / row-group (output)
  int rb = blockIdx.x >> 4;         // row block (256 rows)
  int sp = blockIdx.x & (NSPLIT - 1);
  int wrow   = rb * 256 + wid * 64; // this wave's first row
  int cbase0 = sp * 512;            // this wave's column strip

  float rowPart[16];
  #pragma unroll
  for (int i = 0; i < 16; ++i) rowPart[i] = 0.f;

  for (int citer = 0; citer < 8; ++citer) {
    int colbase = cbase0 + citer * 64;
    f32x4 acc[4][4] = {};
    #pragma unroll 2
    for (int ks = 0; ks < 8; ++ks) {
      int k0 = ks * 32 + g * 8;
      bf16x8 a[4], b[4];
      #pragma unroll
      for (int mi = 0; mi < 4; ++mi)
        a[mi] = *(const bf16x8*)(fn + (size_t)(wrow + mi * 16 + c) * D + k0);
      #pragma unroll
      for (int ni = 0; ni < 4; ++ni)
        b[ni] = *(const bf16x8*)(fn + (size_t)(colbase + ni * 16 + c) * D + k0);
      #pragma unroll
      for (int mi = 0; mi < 4; ++mi)
        #pragma unroll
        for (int ni = 0; ni < 4; ++ni)
          acc[mi][ni] = __builtin_amdgcn_mfma_f32_16x16x32_bf16(
              a[mi], b[ni], acc[mi][ni], 0, 0, 0);
    }
    // epilogue: exp(2*s), zero the diagonal, accumulate per-row sums
    #pragma unroll
    for (int mi = 0; mi < 4; ++mi) {
      #pragma unroll
      for (int ni = 0; ni < 4; ++ni) {
        int gcol = colbase + ni * 16 + c;
        #pragma unroll
        for (int r = 0; r < 4; ++r) {
          int grow = wrow + mi * 16 + g * 4 + r;
          float e = exp2f(acc[mi][ni][r] * C2LOG2E);
          if (grow == gcol) e = 0.f;
          rowPart[mi * 4 + r] += e;
        }
      }
    }
  }
  // sum across the 16 columns held by lanes with same g (bits 0-3 of lane)
  #pragma unroll
  for (int i = 0; i < 16; ++i) {
    float v = rowPart[i];
    v += __shfl_xor(v, 1, 64);
    v += __shfl_xor(v, 2, 64);
    v += __shfl_xor(v, 4, 64);
    v += __shfl_xor(v, 8, 64);
    rowPart[i] = v;
  }
  if (c == 0) {
    #pragma unroll
    for (int mi = 0; mi < 4; ++mi)
      #pragma unroll
      for (int r = 0; r < 4; ++r)
        partial[(size_t)sp * twoN + wrow + mi * 16 + g * 4 + r] =
            rowPart[mi * 4 + r];
  }
}

// ---------------- Kernel C1: per-256-row block sums of log(denom), pos -----
__global__ __launch_bounds__(256) void reduce1_kernel(
    const float* __restrict__ partial, const float* __restrict__ pos,
    float* __restrict__ bsum, int twoN, int N) {
  int row = blockIdx.x * 256 + threadIdx.x;
  int wid = threadIdx.x >> 6, lane = threadIdx.x & 63;
  float denom = 0.f;
  #pragma unroll
  for (int s = 0; s < NSPLIT; ++s) denom += partial[(size_t)s * twoN + row];
  float ld = logf(denom);
  float p  = (row < N) ? pos[row] : 0.f;
  #pragma unroll
  for (int m = 1; m < 64; m <<= 1) {
    ld += __shfl_xor(ld, m, 64);
    p  += __shfl_xor(p, m, 64);
  }
  __shared__ float sld[4], spo[4];
  if (lane == 0) { sld[wid] = ld; spo[wid] = p; }
  __syncthreads();
  if (threadIdx.x == 0) {
    bsum[blockIdx.x]      = sld[0] + sld[1] + sld[2] + sld[3];
    bsum[32 + blockIdx.x] = spo[0] + spo[1] + spo[2] + spo[3];
  }
}

// ---------------- Kernel C2: final scalar loss -----------------------------
__global__ void reduce2_kernel(const float* __restrict__ bsum,
                               float* __restrict__ out, int twoN, int N,
                               int nblk) {
  int t = threadIdx.x;
  float ld = (t < nblk) ? bsum[t] : 0.f;
  float p  = (t < nblk) ? bsum[32 + t] : 0.f;
  #pragma unroll
  for (int m = 1; m < 64; m <<= 1) {
    ld += __shfl_xor(ld, m, 64);
    p  += __shfl_xor(p, m, 64);
  }
  if (t == 0) out[0] = ld / (float)twoN - 2.f * (p / (float)N);
}

extern "C" void kernel_launch(void* const* d_in, const int* in_sizes, int n_in,
                              void* d_out, int out_size, void* d_ws,
                              size_t ws_size, hipStream_t stream) {
  const float* z1 = (const float*)d_in[0];
  const float* z2 = (const float*)d_in[1];
  int N = in_sizes[0] / D;   // 4096
  int twoN = 2 * N;          // 8192

  // workspace layout
  __bf16* fn      = (__bf16*)d_ws;                              // 4 MB
  float*  partial = (float*)((char*)d_ws + (size_t)twoN * D * 2);
  float*  pos     = (float*)((char*)partial + (size_t)NSPLIT * twoN * 4);
  float*  bsum    = (float*)((char*)pos + (size_t)N * 4);       // 64 floats

  normalize_kernel<<<twoN / 4, 256, 0, stream>>>(z1, z2, fn, N);
  pos_kernel<<<N / 4, 256, 0, stream>>>(z1, z2, pos, N);
  denom_kernel<<<(twoN / 256) * NSPLIT, 256, 0, stream>>>(fn, partial, twoN);
  int nblk = twoN / 256;  // 32
  reduce1_kernel<<<nblk, 256, 0, stream>>>(partial, pos, bsum, twoN, N);
  reduce2_kernel<<<1, 64, 0, stream>>>(bsum, (float*)d_out, twoN, N, nblk);
}

// Round 6
// 90.520 us; speedup vs baseline: 1.4930x; 1.4930x over previous
//
#include <hip/hip_runtime.h>

#define D 256
#define C2LOG2E 2.8853900817779268f   // 2 / ln(2): exp(2s) = exp2(s * C2LOG2E)
#define EPS 1e-8f

typedef __attribute__((ext_vector_type(8))) __bf16 bf16x8;
typedef __attribute__((ext_vector_type(4))) __bf16 bf16x4;
typedef __attribute__((ext_vector_type(4))) float  f32x4;

// ---------------- Kernel A: row-normalize [z1;z2] -> bf16 fn ----------------
__global__ __launch_bounds__(256) void normalize_kernel(
    const float* __restrict__ z1, const float* __restrict__ z2,
    __bf16* __restrict__ fn, int N) {
  int wid  = threadIdx.x >> 6;
  int lane = threadIdx.x & 63;
  int row  = blockIdx.x * 4 + wid;
  const float* src = (row < N) ? (z1 + (size_t)row * D)
                               : (z2 + (size_t)(row - N) * D);
  f32x4 v = *(const f32x4*)(src + lane * 4);
  float ss = v.x * v.x + v.y * v.y + v.z * v.z + v.w * v.w;
  #pragma unroll
  for (int m = 1; m < 64; m <<= 1) ss += __shfl_xor(ss, m, 64);
  float inv = 1.0f / fmaxf(sqrtf(ss), EPS);
  bf16x4 o;
  o[0] = (__bf16)(v.x * inv);
  o[1] = (__bf16)(v.y * inv);
  o[2] = (__bf16)(v.z * inv);
  o[3] = (__bf16)(v.w * inv);
  *(bf16x4*)(fn + (size_t)row * D + lane * 4) = o;
}

// ---------------- Kernel P: pos_i = cos(z1_i, z2_i) in fp32 ----------------
__global__ __launch_bounds__(256) void pos_kernel(
    const float* __restrict__ z1, const float* __restrict__ z2,
    float* __restrict__ pos, int N) {
  int wid  = threadIdx.x >> 6;
  int lane = threadIdx.x & 63;
  int row  = blockIdx.x * 4 + wid;
  f32x4 a = *(const f32x4*)(z1 + (size_t)row * D + lane * 4);
  f32x4 b = *(const f32x4*)(z2 + (size_t)row * D + lane * 4);
  float dot = a.x * b.x + a.y * b.y + a.z * b.z + a.w * b.w;
  float n1  = a.x * a.x + a.y * a.y + a.z * a.z + a.w * a.w;
  float n2  = b.x * b.x + b.y * b.y + b.z * b.z + b.w * b.w;
  #pragma unroll
  for (int m = 1; m < 64; m <<= 1) {
    dot += __shfl_xor(dot, m, 64);
    n1  += __shfl_xor(n1, m, 64);
    n2  += __shfl_xor(n2, m, 64);
  }
  if (lane == 0)
    pos[row] = dot / (fmaxf(sqrtf(n1), EPS) * fmaxf(sqrtf(n2), EPS));
}

// -------- Kernel B: denom partials, m97-structure LDS-staged MFMA GEMM -----
// Block = 4 waves, 128x128 output tile, BK=64, double-buffered LDS staged
// via global_load_lds (16B). Chunk swizzle (p ^= row&7) applied as
// inverse-swizzled GLOBAL source + swizzled ds_read (linear LDS dest).
// mfma_f32_16x16x32_bf16: A/B row/col=lane&15, k=(lane>>4)*8+j;
// C/D col=lane&15, row=(lane>>4)*4+reg  (m89/m91-verified).

__device__ __forceinline__ void stage_tile(const __bf16* __restrict__ row0,
                                           int kk, __bf16* lds, int tid) {
  // 128 rows x 64 k (16 KB) = 1024 chunks of 16B; 4 iters x 256 threads.
  #pragma unroll
  for (int it = 0; it < 4; ++it) {
    int s = it * 256 + tid;        // chunk slot; per-wave base + lane*16B ✓
    int r = s >> 3;                // row in tile
    int p = s & 7;                 // chunk-in-row (LDS position)
    const __bf16* src = row0 + (size_t)r * D + kk * 64 + ((p ^ (r & 7)) << 3);
    __builtin_amdgcn_global_load_lds(
        (const __attribute__((address_space(1))) void*)src,
        (__attribute__((address_space(3))) void*)(lds + s * 8), 16, 0, 0);
  }
}

__global__ __launch_bounds__(256) void denom_kernel(
    const __bf16* __restrict__ fn, float* __restrict__ partial, int twoN) {
  __shared__ __bf16 As[2][128 * 64];   // 16 KB each
  __shared__ __bf16 Bs[2][128 * 64];
  __shared__ float  redsum[128][2];

  int tid  = threadIdx.x;
  int wid  = tid >> 6;
  int lane = tid & 63;
  int c = lane & 15;            // frag row/col within 16-tile
  int g = lane >> 4;            // k-group (in) / row-group (out)
  int wr = wid >> 1, wc = wid & 1;
  int nrb = twoN >> 7;          // 64 row-blocks
  int rb = blockIdx.x / nrb;
  int cb = blockIdx.x - rb * nrb;
  const __bf16* Arow0 = fn + (size_t)rb * 128 * D;
  const __bf16* Brow0 = fn + (size_t)cb * 128 * D;

  f32x4 acc[4][4] = {};

  stage_tile(Arow0, 0, As[0], tid);
  stage_tile(Brow0, 0, Bs[0], tid);

  #pragma unroll
  for (int kk = 0; kk < 4; ++kk) {
    int cur = kk & 1;
    if (kk < 3) {
      stage_tile(Arow0, kk + 1, As[cur ^ 1], tid);
      stage_tile(Brow0, kk + 1, Bs[cur ^ 1], tid);
    }
    __syncthreads();   // drains vmcnt before barrier (m97-style)
    #pragma unroll
    for (int ks = 0; ks < 2; ++ks) {
      bf16x8 a[4], b[4];
      #pragma unroll
      for (int mi = 0; mi < 4; ++mi) {
        int ar = wr * 64 + mi * 16 + c;
        a[mi] = *(const bf16x8*)((const char*)As[cur] + ar * 128 +
                                 ((((ks << 2) + g) ^ (ar & 7)) << 4));
      }
      #pragma unroll
      for (int ni = 0; ni < 4; ++ni) {
        int bc = wc * 64 + ni * 16 + c;
        b[ni] = *(const bf16x8*)((const char*)Bs[cur] + bc * 128 +
                                 ((((ks << 2) + g) ^ (bc & 7)) << 4));
      }
      #pragma unroll
      for (int mi = 0; mi < 4; ++mi)
        #pragma unroll
        for (int ni = 0; ni < 4; ++ni)
          acc[mi][ni] = __builtin_amdgcn_mfma_f32_16x16x32_bf16(
              a[mi], b[ni], acc[mi][ni], 0, 0, 0);
    }
    __syncthreads();   // protect buffer before restage
  }

  // epilogue: exp(2*s), zero diagonal, per-row sums over this wave's 64 cols
  float rsum[16];
  #pragma unroll
  for (int i = 0; i < 16; ++i) rsum[i] = 0.f;
  #pragma unroll
  for (int mi = 0; mi < 4; ++mi) {
    #pragma unroll
    for (int ni = 0; ni < 4; ++ni) {
      int gcol = cb * 128 + wc * 64 + ni * 16 + c;
      #pragma unroll
      for (int r = 0; r < 4; ++r) {
        int grow = rb * 128 + wr * 64 + mi * 16 + g * 4 + r;
        float e = exp2f(acc[mi][ni][r] * C2LOG2E);
        if (grow == gcol) e = 0.f;
        rsum[mi * 4 + r] += e;
      }
    }
  }
  // reduce across the 16 column-lanes (bits 0-3 of lane)
  #pragma unroll
  for (int i = 0; i < 16; ++i) {
    float v = rsum[i];
    v += __shfl_xor(v, 1, 64);
    v += __shfl_xor(v, 2, 64);
    v += __shfl_xor(v, 4, 64);
    v += __shfl_xor(v, 8, 64);
    rsum[i] = v;
  }
  if (c == 0) {
    #pragma unroll
    for (int mi = 0; mi < 4; ++mi)
      #pragma unroll
      for (int r = 0; r < 4; ++r)
        redsum[wr * 64 + mi * 16 + g * 4 + r][wc] = rsum[mi * 4 + r];
  }
  __syncthreads();
  if (tid < 128)
    partial[(size_t)cb * twoN + rb * 128 + tid] =
        redsum[tid][0] + redsum[tid][1];
}

// ---------------- Kernel C1: per-256-row block sums of log(denom), pos -----
__global__ __launch_bounds__(256) void reduce1_kernel(
    const float* __restrict__ partial, const float* __restrict__ pos,
    float* __restrict__ bsum, int twoN, int N, int nsplit) {
  int row = blockIdx.x * 256 + threadIdx.x;
  int wid = threadIdx.x >> 6, lane = threadIdx.x & 63;
  float denom = 0.f;
  for (int s = 0; s < nsplit; ++s) denom += partial[(size_t)s * twoN + row];
  float ld = logf(denom);
  float p  = (row < N) ? pos[row] : 0.f;
  #pragma unroll
  for (int m = 1; m < 64; m <<= 1) {
    ld += __shfl_xor(ld, m, 64);
    p  += __shfl_xor(p, m, 64);
  }
  __shared__ float sld[4], spo[4];
  if (lane == 0) { sld[wid] = ld; spo[wid] = p; }
  __syncthreads();
  if (threadIdx.x == 0) {
    bsum[blockIdx.x]      = sld[0] + sld[1] + sld[2] + sld[3];
    bsum[32 + blockIdx.x] = spo[0] + spo[1] + spo[2] + spo[3];
  }
}

// ---------------- Kernel C2: final scalar loss -----------------------------
__global__ void reduce2_kernel(const float* __restrict__ bsum,
                               float* __restrict__ out, int twoN, int N,
                               int nblk) {
  int t = threadIdx.x;
  float ld = (t < nblk) ? bsum[t] : 0.f;
  float p  = (t < nblk) ? bsum[32 + t] : 0.f;
  #pragma unroll
  for (int m = 1; m < 64; m <<= 1) {
    ld += __shfl_xor(ld, m, 64);
    p  += __shfl_xor(p, m, 64);
  }
  if (t == 0) out[0] = ld / (float)twoN - 2.f * (p / (float)N);
}

extern "C" void kernel_launch(void* const* d_in, const int* in_sizes, int n_in,
                              void* d_out, int out_size, void* d_ws,
                              size_t ws_size, hipStream_t stream) {
  const float* z1 = (const float*)d_in[0];
  const float* z2 = (const float*)d_in[1];
  int N = in_sizes[0] / D;   // 4096
  int twoN = 2 * N;          // 8192
  int nrb = twoN / 128;      // 64 (= nsplit)

  // workspace layout
  __bf16* fn      = (__bf16*)d_ws;                               // 4 MB
  float*  partial = (float*)((char*)d_ws + (size_t)twoN * D * 2);// 2 MB
  float*  pos     = (float*)((char*)partial + (size_t)nrb * twoN * 4);
  float*  bsum    = (float*)((char*)pos + (size_t)N * 4);        // 64 floats

  normalize_kernel<<<twoN / 4, 256, 0, stream>>>(z1, z2, fn, N);
  pos_kernel<<<N / 4, 256, 0, stream>>>(z1, z2, pos, N);
  denom_kernel<<<nrb * nrb, 256, 0, stream>>>(fn, partial, twoN);
  int nblk = twoN / 256;  // 32
  reduce1_kernel<<<nblk, 256, 0, stream>>>(partial, pos, bsum, twoN, N, nrb);
  reduce2_kernel<<<1, 64, 0, stream>>>(bsum, (float*)d_out, twoN, N, nblk);
}

// Round 7
// 70.069 us; speedup vs baseline: 1.9288x; 1.2919x over previous
//
#include <hip/hip_runtime.h>

#define D 256
#define C2LOG2E 2.8853900817779268f   // 2 / ln(2): exp(2s) = exp2(s * C2LOG2E)
#define EPS 1e-8f

typedef __attribute__((ext_vector_type(8))) __bf16 bf16x8;
typedef __attribute__((ext_vector_type(4))) __bf16 bf16x4;
typedef __attribute__((ext_vector_type(4))) float  f32x4;

// ---------------- Kernel A: row-normalize [z1;z2] -> bf16 fn ----------------
__global__ __launch_bounds__(256) void normalize_kernel(
    const float* __restrict__ z1, const float* __restrict__ z2,
    __bf16* __restrict__ fn, int N) {
  int wid  = threadIdx.x >> 6;
  int lane = threadIdx.x & 63;
  int row  = blockIdx.x * 4 + wid;
  const float* src = (row < N) ? (z1 + (size_t)row * D)
                               : (z2 + (size_t)(row - N) * D);
  f32x4 v = *(const f32x4*)(src + lane * 4);
  float ss = v.x * v.x + v.y * v.y + v.z * v.z + v.w * v.w;
  #pragma unroll
  for (int m = 1; m < 64; m <<= 1) ss += __shfl_xor(ss, m, 64);
  float inv = 1.0f / fmaxf(sqrtf(ss), EPS);
  bf16x4 o;
  o[0] = (__bf16)(v.x * inv);
  o[1] = (__bf16)(v.y * inv);
  o[2] = (__bf16)(v.z * inv);
  o[3] = (__bf16)(v.w * inv);
  *(bf16x4*)(fn + (size_t)row * D + lane * 4) = o;
}

// ---------------- Kernel P: pos_i = cos(z1_i, z2_i) in fp32 ----------------
__global__ __launch_bounds__(256) void pos_kernel(
    const float* __restrict__ z1, const float* __restrict__ z2,
    float* __restrict__ pos, int N) {
  int wid  = threadIdx.x >> 6;
  int lane = threadIdx.x & 63;
  int row  = blockIdx.x * 4 + wid;
  f32x4 a = *(const f32x4*)(z1 + (size_t)row * D + lane * 4);
  f32x4 b = *(const f32x4*)(z2 + (size_t)row * D + lane * 4);
  float dot = a.x * b.x + a.y * b.y + a.z * b.z + a.w * b.w;
  float n1  = a.x * a.x + a.y * a.y + a.z * a.z + a.w * a.w;
  float n2  = b.x * b.x + b.y * b.y + b.z * b.z + b.w * b.w;
  #pragma unroll
  for (int m = 1; m < 64; m <<= 1) {
    dot += __shfl_xor(dot, m, 64);
    n1  += __shfl_xor(n1, m, 64);
    n2  += __shfl_xor(n2, m, 64);
  }
  if (lane == 0)
    pos[row] = dot / (fmaxf(sqrtf(n1), EPS) * fmaxf(sqrtf(n2), EPS));
}

// -------- Kernel B: denom partials, symmetric upper-triangle MFMA GEMM -----
// sim is symmetric: block (rb,cb) and (cb,rb) tiles are bit-identical (same
// k-order MFMA). Compute only rb<=cb (2080 blocks instead of 4096). Row sums
// of the exp'd tile -> partial[cb][rb-rows]; column sums -> partial[rb][cb-
// rows] (off-diag only). Every (split,rowblock) cell written exactly once.
// m97 structure: 128x128 tile, BK=64, dbuf LDS via global_load_lds(16B),
// chunk swizzle as inverse-swizzled GLOBAL source + swizzled ds_read.
// mfma_f32_16x16x32_bf16: A/B row/col=lane&15, k=(lane>>4)*8+j;
// C/D col=lane&15, row=(lane>>4)*4+reg  (m89/m91-verified).

__device__ __forceinline__ void stage_tile(const __bf16* __restrict__ row0,
                                           int kk, __bf16* lds, int tid) {
  // 128 rows x 64 k (16 KB) = 1024 chunks of 16B; 4 iters x 256 threads.
  #pragma unroll
  for (int it = 0; it < 4; ++it) {
    int s = it * 256 + tid;        // chunk slot; per-wave base + lane*16B ✓
    int r = s >> 3;                // row in tile
    int p = s & 7;                 // chunk-in-row (LDS position)
    const __bf16* src = row0 + (size_t)r * D + kk * 64 + ((p ^ (r & 7)) << 3);
    __builtin_amdgcn_global_load_lds(
        (const __attribute__((address_space(1))) void*)src,
        (__attribute__((address_space(3))) void*)(lds + s * 8), 16, 0, 0);
  }
}

__global__ __launch_bounds__(256) void denom_kernel(
    const __bf16* __restrict__ fn, float* __restrict__ partial, int twoN) {
  __shared__ __bf16 As[2][128 * 64];   // 16 KB each
  __shared__ __bf16 Bs[2][128 * 64];
  __shared__ float  redsumR[128][2];   // row sums, split by wc
  __shared__ float  redsumC[128][2];   // col sums, split by wr

  int tid  = threadIdx.x;
  int wid  = tid >> 6;
  int lane = tid & 63;
  int c = lane & 15;            // frag row/col within 16-tile
  int g = lane >> 4;            // k-group (in) / row-group (out)
  int wr = wid >> 1, wc = wid & 1;

  // decode lower-triangle linear index -> (j<=i), then rb=j, cb=i
  int bid = blockIdx.x;
  int i = (int)((__builtin_sqrt(8.0 * (double)bid + 1.0) - 1.0) * 0.5);
  while ((i + 1) * (i + 2) / 2 <= bid) ++i;
  while (i * (i + 1) / 2 > bid) --i;
  int rb = bid - i * (i + 1) / 2;   // row block  (rb <= cb)
  int cb = i;                       // col block
  const __bf16* Arow0 = fn + (size_t)rb * 128 * D;
  const __bf16* Brow0 = fn + (size_t)cb * 128 * D;

  f32x4 acc[4][4] = {};

  stage_tile(Arow0, 0, As[0], tid);
  stage_tile(Brow0, 0, Bs[0], tid);

  #pragma unroll
  for (int kk = 0; kk < 4; ++kk) {
    int cur = kk & 1;
    if (kk < 3) {
      stage_tile(Arow0, kk + 1, As[cur ^ 1], tid);
      stage_tile(Brow0, kk + 1, Bs[cur ^ 1], tid);
    }
    __syncthreads();   // drains vmcnt before barrier (m97-style)
    #pragma unroll
    for (int ks = 0; ks < 2; ++ks) {
      bf16x8 a[4], b[4];
      #pragma unroll
      for (int mi = 0; mi < 4; ++mi) {
        int ar = wr * 64 + mi * 16 + c;
        a[mi] = *(const bf16x8*)((const char*)As[cur] + ar * 128 +
                                 ((((ks << 2) + g) ^ (ar & 7)) << 4));
      }
      #pragma unroll
      for (int ni = 0; ni < 4; ++ni) {
        int bc = wc * 64 + ni * 16 + c;
        b[ni] = *(const bf16x8*)((const char*)Bs[cur] + bc * 128 +
                                 ((((ks << 2) + g) ^ (bc & 7)) << 4));
      }
      #pragma unroll
      for (int mi = 0; mi < 4; ++mi)
        #pragma unroll
        for (int ni = 0; ni < 4; ++ni)
          acc[mi][ni] = __builtin_amdgcn_mfma_f32_16x16x32_bf16(
              a[mi], b[ni], acc[mi][ni], 0, 0, 0);
    }
    __syncthreads();   // protect buffer before restage
  }

  // epilogue: e=exp(2*s) once; accumulate row sums AND column sums
  float rsum[16];
  float csum[4];
  #pragma unroll
  for (int ii = 0; ii < 16; ++ii) rsum[ii] = 0.f;
  #pragma unroll
  for (int ii = 0; ii < 4; ++ii) csum[ii] = 0.f;
  #pragma unroll
  for (int mi = 0; mi < 4; ++mi) {
    #pragma unroll
    for (int ni = 0; ni < 4; ++ni) {
      int gcol = cb * 128 + wc * 64 + ni * 16 + c;
      #pragma unroll
      for (int r = 0; r < 4; ++r) {
        int grow = rb * 128 + wr * 64 + mi * 16 + g * 4 + r;
        float e = exp2f(acc[mi][ni][r] * C2LOG2E);
        if (grow == gcol) e = 0.f;
        rsum[mi * 4 + r] += e;   // row sum (over this wave's 64 cols)
        csum[ni]         += e;   // col sum (over this wave's 64 rows)
      }
    }
  }
  // row sums: reduce across the 16 column-lanes (bits 0-3 of lane)
  #pragma unroll
  for (int ii = 0; ii < 16; ++ii) {
    float v = rsum[ii];
    v += __shfl_xor(v, 1, 64);
    v += __shfl_xor(v, 2, 64);
    v += __shfl_xor(v, 4, 64);
    v += __shfl_xor(v, 8, 64);
    rsum[ii] = v;
  }
  // col sums: reduce across the 4 row-groups g (bits 4-5 of lane)
  #pragma unroll
  for (int ii = 0; ii < 4; ++ii) {
    float v = csum[ii];
    v += __shfl_xor(v, 16, 64);
    v += __shfl_xor(v, 32, 64);
    csum[ii] = v;
  }
  if (c == 0) {
    #pragma unroll
    for (int mi = 0; mi < 4; ++mi)
      #pragma unroll
      for (int r = 0; r < 4; ++r)
        redsumR[wr * 64 + mi * 16 + g * 4 + r][wc] = rsum[mi * 4 + r];
  }
  if (g == 0) {
    #pragma unroll
    for (int ni = 0; ni < 4; ++ni)
      redsumC[wc * 64 + ni * 16 + c][wr] = csum[ni];
  }
  __syncthreads();
  if (tid < 128) {
    partial[(size_t)cb * twoN + rb * 128 + tid] =
        redsumR[tid][0] + redsumR[tid][1];
    if (rb != cb)
      partial[(size_t)rb * twoN + cb * 128 + tid] =
          redsumC[tid][0] + redsumC[tid][1];
  }
}

// ---------------- Kernel C1: per-256-row block sums of log(denom), pos -----
__global__ __launch_bounds__(256) void reduce1_kernel(
    const float* __restrict__ partial, const float* __restrict__ pos,
    float* __restrict__ bsum, int twoN, int N, int nsplit) {
  int row = blockIdx.x * 256 + threadIdx.x;
  int wid = threadIdx.x >> 6, lane = threadIdx.x & 63;
  float denom = 0.f;
  for (int s = 0; s < nsplit; ++s) denom += partial[(size_t)s * twoN + row];
  float ld = logf(denom);
  float p  = (row < N) ? pos[row] : 0.f;
  #pragma unroll
  for (int m = 1; m < 64; m <<= 1) {
    ld += __shfl_xor(ld, m, 64);
    p  += __shfl_xor(p, m, 64);
  }
  __shared__ float sld[4], spo[4];
  if (lane == 0) { sld[wid] = ld; spo[wid] = p; }
  __syncthreads();
  if (threadIdx.x == 0) {
    bsum[blockIdx.x]      = sld[0] + sld[1] + sld[2] + sld[3];
    bsum[32 + blockIdx.x] = spo[0] + spo[1] + spo[2] + spo[3];
  }
}

// ---------------- Kernel C2: final scalar loss -----------------------------
__global__ void reduce2_kernel(const float* __restrict__ bsum,
                               float* __restrict__ out, int twoN, int N,
                               int nblk) {
  int t = threadIdx.x;
  float ld = (t < nblk) ? bsum[t] : 0.f;
  float p  = (t < nblk) ? bsum[32 + t] : 0.f;
  #pragma unroll
  for (int m = 1; m < 64; m <<= 1) {
    ld += __shfl_xor(ld, m, 64);
    p  += __shfl_xor(p, m, 64);
  }
  if (t == 0) out[0] = ld / (float)twoN - 2.f * (p / (float)N);
}

extern "C" void kernel_launch(void* const* d_in, const int* in_sizes, int n_in,
                              void* d_out, int out_size, void* d_ws,
                              size_t ws_size, hipStream_t stream) {
  const float* z1 = (const float*)d_in[0];
  const float* z2 = (const float*)d_in[1];
  int N = in_sizes[0] / D;   // 4096
  int twoN = 2 * N;          // 8192
  int nrb = twoN / 128;      // 64 (= nsplit)

  // workspace layout
  __bf16* fn      = (__bf16*)d_ws;                               // 4 MB
  float*  partial = (float*)((char*)d_ws + (size_t)twoN * D * 2);// 2 MB
  float*  pos     = (float*)((char*)partial + (size_t)nrb * twoN * 4);
  float*  bsum    = (float*)((char*)pos + (size_t)N * 4);        // 64 floats

  normalize_kernel<<<twoN / 4, 256, 0, stream>>>(z1, z2, fn, N);
  pos_kernel<<<N / 4, 256, 0, stream>>>(z1, z2, pos, N);
  int ntri = nrb * (nrb + 1) / 2;  // 2080 upper-triangle blocks
  denom_kernel<<<ntri, 256, 0, stream>>>(fn, partial, twoN);
  int nblk = twoN / 256;  // 32
  reduce1_kernel<<<nblk, 256, 0, stream>>>(partial, pos, bsum, twoN, N, nrb);
  reduce2_kernel<<<1, 64, 0, stream>>>(bsum, (float*)d_out, twoN, N, nblk);
}

// Round 8
// 60.173 us; speedup vs baseline: 2.2460x; 1.1645x over previous
//
#include <hip/hip_runtime.h>

#define D 256
#define C2LOG2E 2.8853900817779268f   // 2 / ln(2): exp(2s) = exp2(s * C2LOG2E)
#define EPS 1e-8f

typedef __attribute__((ext_vector_type(8))) __bf16 bf16x8;
typedef __attribute__((ext_vector_type(4))) __bf16 bf16x4;
typedef __attribute__((ext_vector_type(4))) float  f32x4;

// ------ Kernel A: row-normalize [z1;z2] -> bf16 fn, fused pos_i (fp32) -----
// One wave per row-pair (z1_i, z2_i): both norms + dot in one shuffle chain.
__global__ __launch_bounds__(256) void normpos_kernel(
    const float* __restrict__ z1, const float* __restrict__ z2,
    __bf16* __restrict__ fn, float* __restrict__ pos, int N) {
  int wid  = threadIdx.x >> 6;
  int lane = threadIdx.x & 63;
  int row  = blockIdx.x * 4 + wid;
  f32x4 a = *(const f32x4*)(z1 + (size_t)row * D + lane * 4);
  f32x4 b = *(const f32x4*)(z2 + (size_t)row * D + lane * 4);
  float s1  = a.x * a.x + a.y * a.y + a.z * a.z + a.w * a.w;
  float s2  = b.x * b.x + b.y * b.y + b.z * b.z + b.w * b.w;
  float dot = a.x * b.x + a.y * b.y + a.z * b.z + a.w * b.w;
  #pragma unroll
  for (int m = 1; m < 64; m <<= 1) {
    s1  += __shfl_xor(s1, m, 64);
    s2  += __shfl_xor(s2, m, 64);
    dot += __shfl_xor(dot, m, 64);
  }
  float inv1 = 1.0f / fmaxf(sqrtf(s1), EPS);
  float inv2 = 1.0f / fmaxf(sqrtf(s2), EPS);
  bf16x4 o1, o2;
  o1[0] = (__bf16)(a.x * inv1); o1[1] = (__bf16)(a.y * inv1);
  o1[2] = (__bf16)(a.z * inv1); o1[3] = (__bf16)(a.w * inv1);
  o2[0] = (__bf16)(b.x * inv2); o2[1] = (__bf16)(b.y * inv2);
  o2[2] = (__bf16)(b.z * inv2); o2[3] = (__bf16)(b.w * inv2);
  *(bf16x4*)(fn + (size_t)row * D + lane * 4)       = o1;
  *(bf16x4*)(fn + (size_t)(N + row) * D + lane * 4) = o2;
  if (lane == 0) pos[row] = dot * inv1 * inv2;
}

// -------- Kernel B: denom partials, symmetric upper-triangle MFMA GEMM -----
// True m97 structure: SINGLE-buffered LDS (34.5 KB -> 4 blocks/CU, 16
// waves/CU); cross-block wave overlap hides the exposed stage (m114).
// sim symmetric: compute rb<=cb only; row sums -> partial[cb][rb-rows],
// col sums -> partial[rb][cb-rows]. Chunk swizzle as inverse-swizzled
// GLOBAL source + swizzled ds_read (linear LDS dest, rule #21).
// mfma_f32_16x16x32_bf16: A/B row/col=lane&15, k=(lane>>4)*8+j;
// C/D col=lane&15, row=(lane>>4)*4+reg  (m89/m91-verified).

__device__ __forceinline__ void stage_tile(const __bf16* __restrict__ row0,
                                           int kk, __bf16* lds, int tid) {
  // 128 rows x 64 k (16 KB) = 1024 chunks of 16B; 4 iters x 256 threads.
  #pragma unroll
  for (int it = 0; it < 4; ++it) {
    int s = it * 256 + tid;        // chunk slot; per-wave base + lane*16B ✓
    int r = s >> 3;                // row in tile
    int p = s & 7;                 // chunk-in-row (LDS position)
    const __bf16* src = row0 + (size_t)r * D + kk * 64 + ((p ^ (r & 7)) << 3);
    __builtin_amdgcn_global_load_lds(
        (const __attribute__((address_space(1))) void*)src,
        (__attribute__((address_space(3))) void*)(lds + s * 8), 16, 0, 0);
  }
}

__global__ __launch_bounds__(256, 4) void denom_kernel(
    const __bf16* __restrict__ fn, float* __restrict__ partial, int twoN) {
  __shared__ __bf16 As[128 * 64];      // 16 KB (single-buffered)
  __shared__ __bf16 Bs[128 * 64];      // 16 KB
  __shared__ float  redsumR[128][2];   // row sums, split by wc
  __shared__ float  redsumC[128][2];   // col sums, split by wr

  int tid  = threadIdx.x;
  int wid  = tid >> 6;
  int lane = tid & 63;
  int c = lane & 15;            // frag row/col within 16-tile
  int g = lane >> 4;            // k-group (in) / row-group (out)
  int wr = wid >> 1, wc = wid & 1;

  // decode lower-triangle linear index -> (rb<=cb)
  int bid = blockIdx.x;
  int i = (int)((sqrtf(8.f * (float)bid + 1.f) - 1.f) * 0.5f);
  while ((i + 1) * (i + 2) / 2 <= bid) ++i;
  while (i * (i + 1) / 2 > bid) --i;
  int rb = bid - i * (i + 1) / 2;   // row block  (rb <= cb)
  int cb = i;                       // col block
  const __bf16* Arow0 = fn + (size_t)rb * 128 * D;
  const __bf16* Brow0 = fn + (size_t)cb * 128 * D;

  f32x4 acc[4][4] = {};

  stage_tile(Arow0, 0, As, tid);
  stage_tile(Brow0, 0, Bs, tid);

  #pragma unroll
  for (int kk = 0; kk < 4; ++kk) {
    __syncthreads();   // stage complete (vmcnt drained before barrier)
    #pragma unroll
    for (int ks = 0; ks < 2; ++ks) {
      bf16x8 a[4], b[4];
      #pragma unroll
      for (int mi = 0; mi < 4; ++mi) {
        int ar = wr * 64 + mi * 16 + c;
        a[mi] = *(const bf16x8*)((const char*)As + ar * 128 +
                                 ((((ks << 2) + g) ^ (ar & 7)) << 4));
      }
      #pragma unroll
      for (int ni = 0; ni < 4; ++ni) {
        int bc = wc * 64 + ni * 16 + c;
        b[ni] = *(const bf16x8*)((const char*)Bs + bc * 128 +
                                 ((((ks << 2) + g) ^ (bc & 7)) << 4));
      }
      #pragma unroll
      for (int mi = 0; mi < 4; ++mi)
        #pragma unroll
        for (int ni = 0; ni < 4; ++ni)
          acc[mi][ni] = __builtin_amdgcn_mfma_f32_16x16x32_bf16(
              a[mi], b[ni], acc[mi][ni], 0, 0, 0);
    }
    if (kk < 3) {
      __syncthreads();               // protect LDS before restage
      stage_tile(Arow0, kk + 1, As, tid);
      stage_tile(Brow0, kk + 1, Bs, tid);
    }
  }

  // epilogue: e=exp(2*s) once; accumulate row sums AND column sums
  float rsum[16];
  float csum[4];
  #pragma unroll
  for (int ii = 0; ii < 16; ++ii) rsum[ii] = 0.f;
  #pragma unroll
  for (int ii = 0; ii < 4; ++ii) csum[ii] = 0.f;
  #pragma unroll
  for (int mi = 0; mi < 4; ++mi) {
    #pragma unroll
    for (int ni = 0; ni < 4; ++ni) {
      int gcol = cb * 128 + wc * 64 + ni * 16 + c;
      #pragma unroll
      for (int r = 0; r < 4; ++r) {
        int grow = rb * 128 + wr * 64 + mi * 16 + g * 4 + r;
        float e = __builtin_amdgcn_exp2f(acc[mi][ni][r] * C2LOG2E);
        if (grow == gcol) e = 0.f;
        rsum[mi * 4 + r] += e;   // row sum (over this wave's 64 cols)
        csum[ni]         += e;   // col sum (over this wave's 64 rows)
      }
    }
  }
  // row sums: reduce across the 16 column-lanes (bits 0-3 of lane)
  #pragma unroll
  for (int ii = 0; ii < 16; ++ii) {
    float v = rsum[ii];
    v += __shfl_xor(v, 1, 64);
    v += __shfl_xor(v, 2, 64);
    v += __shfl_xor(v, 4, 64);
    v += __shfl_xor(v, 8, 64);
    rsum[ii] = v;
  }
  // col sums: reduce across the 4 row-groups g (bits 4-5 of lane)
  #pragma unroll
  for (int ii = 0; ii < 4; ++ii) {
    float v = csum[ii];
    v += __shfl_xor(v, 16, 64);
    v += __shfl_xor(v, 32, 64);
    csum[ii] = v;
  }
  if (c == 0) {
    #pragma unroll
    for (int mi = 0; mi < 4; ++mi)
      #pragma unroll
      for (int r = 0; r < 4; ++r)
        redsumR[wr * 64 + mi * 16 + g * 4 + r][wc] = rsum[mi * 4 + r];
  }
  if (g == 0) {
    #pragma unroll
    for (int ni = 0; ni < 4; ++ni)
      redsumC[wc * 64 + ni * 16 + c][wr] = csum[ni];
  }
  __syncthreads();
  if (tid < 128) {
    partial[(size_t)cb * twoN + rb * 128 + tid] =
        redsumR[tid][0] + redsumR[tid][1];
    if (rb != cb)
      partial[(size_t)rb * twoN + cb * 128 + tid] =
          redsumC[tid][0] + redsumC[tid][1];
  }
}

// ---------------- Kernel C1: per-256-row block sums of log(denom), pos -----
__global__ __launch_bounds__(256) void reduce1_kernel(
    const float* __restrict__ partial, const float* __restrict__ pos,
    float* __restrict__ bsum, int twoN, int N, int nsplit) {
  int row = blockIdx.x * 256 + threadIdx.x;
  int wid = threadIdx.x >> 6, lane = threadIdx.x & 63;
  float denom = 0.f;
  for (int s = 0; s < nsplit; ++s) denom += partial[(size_t)s * twoN + row];
  float ld = logf(denom);
  float p  = (row < N) ? pos[row] : 0.f;
  #pragma unroll
  for (int m = 1; m < 64; m <<= 1) {
    ld += __shfl_xor(ld, m, 64);
    p  += __shfl_xor(p, m, 64);
  }
  __shared__ float sld[4], spo[4];
  if (lane == 0) { sld[wid] = ld; spo[wid] = p; }
  __syncthreads();
  if (threadIdx.x == 0) {
    bsum[blockIdx.x]      = sld[0] + sld[1] + sld[2] + sld[3];
    bsum[32 + blockIdx.x] = spo[0] + spo[1] + spo[2] + spo[3];
  }
}

// ---------------- Kernel C2: final scalar loss -----------------------------
__global__ void reduce2_kernel(const float* __restrict__ bsum,
                               float* __restrict__ out, int twoN, int N,
                               int nblk) {
  int t = threadIdx.x;
  float ld = (t < nblk) ? bsum[t] : 0.f;
  float p  = (t < nblk) ? bsum[32 + t] : 0.f;
  #pragma unroll
  for (int m = 1; m < 64; m <<= 1) {
    ld += __shfl_xor(ld, m, 64);
    p  += __shfl_xor(p, m, 64);
  }
  if (t == 0) out[0] = ld / (float)twoN - 2.f * (p / (float)N);
}

extern "C" void kernel_launch(void* const* d_in, const int* in_sizes, int n_in,
                              void* d_out, int out_size, void* d_ws,
                              size_t ws_size, hipStream_t stream) {
  const float* z1 = (const float*)d_in[0];
  const float* z2 = (const float*)d_in[1];
  int N = in_sizes[0] / D;   // 4096
  int twoN = 2 * N;          // 8192
  int nrb = twoN / 128;      // 64 (= nsplit)

  // workspace layout
  __bf16* fn      = (__bf16*)d_ws;                               // 4 MB
  float*  partial = (float*)((char*)d_ws + (size_t)twoN * D * 2);// 2 MB
  float*  pos     = (float*)((char*)partial + (size_t)nrb * twoN * 4);
  float*  bsum    = (float*)((char*)pos + (size_t)N * 4);        // 64 floats

  normpos_kernel<<<N / 4, 256, 0, stream>>>(z1, z2, fn, pos, N);
  int ntri = nrb * (nrb + 1) / 2;  // 2080 upper-triangle blocks
  denom_kernel<<<ntri, 256, 0, stream>>>(fn, partial, twoN);
  int nblk = twoN / 256;  // 32
  reduce1_kernel<<<nblk, 256, 0, stream>>>(partial, pos, bsum, twoN, N, nrb);
  reduce2_kernel<<<1, 64, 0, stream>>>(bsum, (float*)d_out, twoN, N, nblk);
}